// Round 10
// baseline (642.622 us; speedup 1.0000x reference)
//
#include <hip/hip_runtime.h>
#include <hip/hip_bf16.h>

#define FRAMES 512
#define BATCH 2048
#define IN_DIM 84
#define HIDDEN 300
#define OUT_DIM 10

#define MT 16            // batch rows per workgroup
#define RSTR 512         // row stride in shorts (g(r,c) = r*512 + 8*(r&7) + c)
#define KFH 10           // h K-fragments (K=320, k 300..319 zero-weighted pad)
#define BUFS (MT * RSTR) // shorts per buffer (16 KiB)
#define NT 3             // tiles per wave: t = wv, wv+8, wv+16 (wv>=3 -> 2 real)

typedef __attribute__((ext_vector_type(8))) short s8v;
typedef __attribute__((ext_vector_type(4))) short s4v;
typedef __attribute__((ext_vector_type(4))) float f4v;

__device__ __forceinline__ short f2b(float x) {
    __hip_bfloat16 h = __float2bfloat16(x);
    return *reinterpret_cast<short*>(&h);
}
__device__ __forceinline__ float b2f(short s) {
    __hip_bfloat16 h = *reinterpret_cast<__hip_bfloat16*>(&s);
    return __bfloat162float(h);
}
__device__ __forceinline__ float fast_tanh(float z) {
    float ex = __builtin_amdgcn_exp2f(z * 2.88539008177792681f); // exp(2z)
    return fmaf(-2.f, __builtin_amdgcn_rcpf(ex + 1.f), 1.f);
}
__device__ __forceinline__ int g(int r, int c) {   // swizzled LDS index (shorts)
    return r * RSTR + ((r & 7) << 3) + c;          // linear in c
}
__device__ __forceinline__ void lgkm_barrier() {   // no vmcnt drain at barrier
    asm volatile("s_waitcnt lgkmcnt(0)" ::: "memory");
    __builtin_amdgcn_s_barrier();
}
__device__ __forceinline__ s8v cvt8(float4 a, float4 b) {
    s8v v;
    v[0] = f2b(a.x); v[1] = f2b(a.y); v[2] = f2b(a.z); v[3] = f2b(a.w);
    v[4] = f2b(b.x); v[5] = f2b(b.y); v[6] = f2b(b.z); v[7] = f2b(b.w);
    return v;
}

// Swapped-operand step:  D[n][b] = sum_k W[n][k] * state[b][k]
//   k 0..319: h (LDS, 10 b128 frags);  k "320..415": x (HBM->register frags,
//   lane l loads x[b0+(l&15)][(l>>4)*8 + j + 32c] as 2 aligned float4 per frag;
//   x slab (5.4 KB) is L1-resident so the 8-wave re-read never touches HBM twice).
//   C/D: lane l holds batch=l&15, 4 consecutive n -> one ds_write_b64 per tile;
//   tile 18's n=300..303 lands in the zero-weighted LDS pad (harmless, no mask).

__global__ __launch_bounds__(512, 2)
void rnn_kernel(const float* __restrict__ x, const float* __restrict__ h0,
                const float* __restrict__ Wi, const float* __restrict__ Wh,
                const float* __restrict__ Wo, float* __restrict__ out)
{
    __shared__ short lds[2 * BUFS];
    const int tid  = threadIdx.x;
    const int lane = tid & 63;
    const int wv   = tid >> 6;          // wave 0..7
    const int l15  = lane & 15;
    const int lkhi = lane >> 4;         // k-subchunk 0..3 / n_local quad
    const int b0   = blockIdx.x * MT;
    const bool w3  = (wv < 3);          // third tile (t = wv+16 <= 18) real

    // ---- weight-stationary A-fragments: kf 0..9 = Wh (K=320), 10..12 = Wi ----
    s8v w[NT][13];
#pragma unroll
    for (int i = 0; i < NT; ++i) {
        const int n = (wv + 8 * i) * 16 + l15;
#pragma unroll
        for (int kf = 0; kf < KFH; ++kf) {
            s8v v;
#pragma unroll
            for (int j = 0; j < 8; ++j) {
                int k = kf * 32 + lkhi * 8 + j;
                float f = (n < HIDDEN && k < HIDDEN) ? Wh[n * HIDDEN + k] : 0.f;
                v[j] = f2b(f);
            }
            w[i][kf] = v;
        }
#pragma unroll
        for (int kf = KFH; kf < 13; ++kf) {
            s8v v;
#pragma unroll
            for (int j = 0; j < 8; ++j) {
                int k = (kf - KFH) * 32 + lkhi * 8 + j;
                float f = (n < HIDDEN && k < IN_DIM) ? Wi[n * IN_DIM + k] : 0.f;
                v[j] = f2b(f);
            }
            w[i][kf] = v;
        }
    }

    // ---- zero both buffers (pad cols must be finite: they meet zero weights) ----
    {
        s4v z = (s4v){0, 0, 0, 0};
        for (int i = tid; i < 2 * BUFS / 4; i += 512)
            ((s4v*)lds)[i] = z;
    }
    __syncthreads();

    // ---- h0 -> buf0 ----
    for (int i = tid; i < MT * HIDDEN; i += 512) {
        int r = i / HIDDEN, c = i % HIDDEN;
        lds[g(r, c)] = f2b(h0[(size_t)(b0 + r) * HIDDEN + c]);
    }

    // ---- per-lane constant bases ----
    const int rdh = g(l15, lkhi * 8);            // h B-frag read base (+kf*32)
    const int wrb = g(l15, lkhi * 4);            // h' write base (+t*16)
    const float* xrow = x + (size_t)(b0 + l15) * IN_DIM + lkhi * 8;  // + frame*BATCH*IN_DIM
    const bool ld4 = (lkhi < 3), ld5 = (lkhi < 2);
    const f4v zero4 = (f4v){0.f, 0.f, 0.f, 0.f};

    // ---- x fragment state: frame 0 (inactive-lane xf4/xf5 stay zero forever) ----
    float4 xf0, xf1, xf2, xf3;
    float4 xf4 = {0.f, 0.f, 0.f, 0.f}, xf5 = {0.f, 0.f, 0.f, 0.f};
    xf0 = *(const float4*)(xrow);
    xf1 = *(const float4*)(xrow + 4);
    xf2 = *(const float4*)(xrow + 32);
    xf3 = *(const float4*)(xrow + 36);
    if (ld4) xf4 = *(const float4*)(xrow + 64);   // lkhi==2: xk 80..83 (last valid)
    if (ld5) xf5 = *(const float4*)(xrow + 68);
    s8v xA0 = cvt8(xf0, xf1), xA1 = cvt8(xf2, xf3), xA2 = cvt8(xf4, xf5);
    __syncthreads();

    // STEP: uses x-frags of frame SF; LOADF -> load frame SF+1 (cvt at step end)
#define STEP(PH, SF, LOADF)                                                     \
    {                                                                           \
        if (LOADF) {                                                            \
            const float* r_ = xrow + (size_t)((SF) + 1) * (BATCH * IN_DIM);     \
            xf0 = *(const float4*)(r_);                                         \
            xf1 = *(const float4*)(r_ + 4);                                     \
            xf2 = *(const float4*)(r_ + 32);                                    \
            xf3 = *(const float4*)(r_ + 36);                                    \
            if (ld4) xf4 = *(const float4*)(r_ + 64);                           \
            if (ld5) xf5 = *(const float4*)(r_ + 68);                           \
        }                                                                       \
        s8v bf[KFH];                                                            \
        _Pragma("unroll")                                                       \
        for (int kf = 0; kf < KFH; ++kf)                                        \
            bf[kf] = *(const s8v*)&lds[(PH) * BUFS + rdh + kf * 32];            \
        __builtin_amdgcn_s_setprio(1);                                          \
        if (w3) {                                                               \
            f4v a0 = __builtin_amdgcn_mfma_f32_16x16x32_bf16(w[0][0], bf[0], zero4, 0, 0, 0); \
            f4v a1 = __builtin_amdgcn_mfma_f32_16x16x32_bf16(w[1][0], bf[0], zero4, 0, 0, 0); \
            f4v a2 = __builtin_amdgcn_mfma_f32_16x16x32_bf16(w[2][0], bf[0], zero4, 0, 0, 0); \
            _Pragma("unroll")                                                   \
            for (int kf = 1; kf < KFH; ++kf) {                                  \
                a0 = __builtin_amdgcn_mfma_f32_16x16x32_bf16(w[0][kf], bf[kf], a0, 0, 0, 0); \
                a1 = __builtin_amdgcn_mfma_f32_16x16x32_bf16(w[1][kf], bf[kf], a1, 0, 0, 0); \
                a2 = __builtin_amdgcn_mfma_f32_16x16x32_bf16(w[2][kf], bf[kf], a2, 0, 0, 0); \
            }                                                                   \
            a0 = __builtin_amdgcn_mfma_f32_16x16x32_bf16(w[0][10], xA0, a0, 0, 0, 0); \
            a1 = __builtin_amdgcn_mfma_f32_16x16x32_bf16(w[1][10], xA0, a1, 0, 0, 0); \
            a2 = __builtin_amdgcn_mfma_f32_16x16x32_bf16(w[2][10], xA0, a2, 0, 0, 0); \
            a0 = __builtin_amdgcn_mfma_f32_16x16x32_bf16(w[0][11], xA1, a0, 0, 0, 0); \
            a1 = __builtin_amdgcn_mfma_f32_16x16x32_bf16(w[1][11], xA1, a1, 0, 0, 0); \
            a2 = __builtin_amdgcn_mfma_f32_16x16x32_bf16(w[2][11], xA1, a2, 0, 0, 0); \
            a0 = __builtin_amdgcn_mfma_f32_16x16x32_bf16(w[0][12], xA2, a0, 0, 0, 0); \
            a1 = __builtin_amdgcn_mfma_f32_16x16x32_bf16(w[1][12], xA2, a1, 0, 0, 0); \
            a2 = __builtin_amdgcn_mfma_f32_16x16x32_bf16(w[2][12], xA2, a2, 0, 0, 0); \
            __builtin_amdgcn_s_setprio(0);                                      \
            s4v h0v, h1v, h2v;                                                  \
            _Pragma("unroll")                                                   \
            for (int r = 0; r < 4; ++r) {                                       \
                h0v[r] = f2b(fast_tanh(a0[r]));                                 \
                h1v[r] = f2b(fast_tanh(a1[r]));                                 \
                h2v[r] = f2b(fast_tanh(a2[r]));                                 \
            }                                                                   \
            *(s4v*)&lds[((PH) ^ 1) * BUFS + wrb + (wv)      * 16] = h0v;        \
            *(s4v*)&lds[((PH) ^ 1) * BUFS + wrb + (wv + 8)  * 16] = h1v;        \
            *(s4v*)&lds[((PH) ^ 1) * BUFS + wrb + (wv + 16) * 16] = h2v;        \
        } else {                                                                \
            f4v a0 = __builtin_amdgcn_mfma_f32_16x16x32_bf16(w[0][0], bf[0], zero4, 0, 0, 0); \
            f4v a1 = __builtin_amdgcn_mfma_f32_16x16x32_bf16(w[1][0], bf[0], zero4, 0, 0, 0); \
            _Pragma("unroll")                                                   \
            for (int kf = 1; kf < KFH; ++kf) {                                  \
                a0 = __builtin_amdgcn_mfma_f32_16x16x32_bf16(w[0][kf], bf[kf], a0, 0, 0, 0); \
                a1 = __builtin_amdgcn_mfma_f32_16x16x32_bf16(w[1][kf], bf[kf], a1, 0, 0, 0); \
            }                                                                   \
            a0 = __builtin_amdgcn_mfma_f32_16x16x32_bf16(w[0][10], xA0, a0, 0, 0, 0); \
            a1 = __builtin_amdgcn_mfma_f32_16x16x32_bf16(w[1][10], xA0, a1, 0, 0, 0); \
            a0 = __builtin_amdgcn_mfma_f32_16x16x32_bf16(w[0][11], xA1, a0, 0, 0, 0); \
            a1 = __builtin_amdgcn_mfma_f32_16x16x32_bf16(w[1][11], xA1, a1, 0, 0, 0); \
            a0 = __builtin_amdgcn_mfma_f32_16x16x32_bf16(w[0][12], xA2, a0, 0, 0, 0); \
            a1 = __builtin_amdgcn_mfma_f32_16x16x32_bf16(w[1][12], xA2, a1, 0, 0, 0); \
            __builtin_amdgcn_s_setprio(0);                                      \
            s4v h0v, h1v;                                                       \
            _Pragma("unroll")                                                   \
            for (int r = 0; r < 4; ++r) {                                       \
                h0v[r] = f2b(fast_tanh(a0[r]));                                 \
                h1v[r] = f2b(fast_tanh(a1[r]));                                 \
            }                                                                   \
            *(s4v*)&lds[((PH) ^ 1) * BUFS + wrb + (wv)     * 16] = h0v;         \
            *(s4v*)&lds[((PH) ^ 1) * BUFS + wrb + (wv + 8) * 16] = h1v;         \
        }                                                                       \
        if (LOADF) {   /* convert frame SF+1 loads (landed during compute) */   \
            xA0 = cvt8(xf0, xf1); xA1 = cvt8(xf2, xf3); xA2 = cvt8(xf4, xf5);   \
        }                                                                       \
        lgkm_barrier();                                                         \
    }

    for (int s = 0; s < FRAMES - 2; s += 2) {
        STEP(0, s,     1)
        STEP(1, s + 1, 1)
    }
    STEP(0, 510, 1)   // loads+converts frame 511
    STEP(1, 511, 0)   // last step, no load
#undef STEP

    // ---- epilogue: final h in buf0 (FRAMES even) ----
    float* hout = out + BATCH * OUT_DIM;
    for (int i = tid; i < MT * HIDDEN; i += 512) {
        int r = i / HIDDEN, c = i % HIDDEN;
        hout[(size_t)(b0 + r) * HIDDEN + c] = b2f(lds[g(r, c)]);
    }
    if (tid < MT * OUT_DIM) {
        int r = tid / OUT_DIM, c = tid % OUT_DIM;
        float sum = 0.f;
        for (int k = 0; k < HIDDEN; ++k)
            sum = fmaf(b2f(lds[g(r, k)]), Wo[c * HIDDEN + k], sum);
        out[(b0 + r) * OUT_DIM + c] = sum;
    }
}

extern "C" void kernel_launch(void* const* d_in, const int* in_sizes, int n_in,
                              void* d_out, int out_size, void* d_ws, size_t ws_size,
                              hipStream_t stream) {
    const float* x  = (const float*)d_in[0];
    const float* h0 = (const float*)d_in[1];
    const float* Wi = (const float*)d_in[2];
    const float* Wh = (const float*)d_in[3];
    const float* Wo = (const float*)d_in[4];
    float* out = (float*)d_out;
    rnn_kernel<<<dim3(BATCH / MT), dim3(512), 0, stream>>>(x, h0, Wi, Wh, Wo, out);
}

// Round 11
// 530.819 us; speedup vs baseline: 1.2106x; 1.2106x over previous
//
#include <hip/hip_runtime.h>
#include <hip/hip_bf16.h>

#define FRAMES 512
#define BATCH 2048
#define IN_DIM 84
#define HIDDEN 300
#define OUT_DIM 10

#define MT 16            // batch rows per workgroup
#define RSTR 512         // row stride in shorts (g(r,c) = r*512 + 8*(r&7) + c)
#define XK 300           // x starts at k=300: K = 300 h + 84 x = 384 = 12*32 exactly
#define KF 12            // K-fragments per step
#define BUFS (MT * RSTR) // shorts per buffer (16 KiB)
#define NT 3             // tiles per wave: t = wv, wv+8, wv+16 (wv>=3 -> 2 real tiles)

typedef __attribute__((ext_vector_type(8))) short s8v;
typedef __attribute__((ext_vector_type(4))) short s4v;
typedef __attribute__((ext_vector_type(4))) float f4v;

__device__ __forceinline__ short f2b(float x) {
    __hip_bfloat16 h = __float2bfloat16(x);
    return *reinterpret_cast<short*>(&h);
}
__device__ __forceinline__ float b2f(short s) {
    __hip_bfloat16 h = *reinterpret_cast<__hip_bfloat16*>(&s);
    return __bfloat162float(h);
}
__device__ __forceinline__ float fast_tanh(float z) {
    float ex = __builtin_amdgcn_exp2f(z * 2.88539008177792681f); // exp(2z)
    return fmaf(-2.f, __builtin_amdgcn_rcpf(ex + 1.f), 1.f);
}
__device__ __forceinline__ int g(int r, int c) {   // swizzled LDS index (shorts)
    return r * RSTR + ((r & 7) << 3) + c;          // linear in c
}
__device__ __forceinline__ void lgkm_barrier() {   // no vmcnt drain at barrier
    asm volatile("s_waitcnt lgkmcnt(0)" ::: "memory");
    __builtin_amdgcn_s_barrier();
}

// Swapped-operand step:  D[n][b] = sum_k W[n][k] * state[b][k],  K = 384
//   state[b][k] = h[b][k] (k<300) | x[b][k-300] (k>=300); weights likewise.
//   C/D: lane l holds batch=l&15, 4 consecutive n -> one ds_write_b64 per tile.
//   Tile 18 covers n 288..303: lanes n>=300 (wv==2,lkhi==3) masked (x lives there).
// Skewed chains: a0 leads a1 by 4 kf, a2 by 8 kf -> tanh0 issues while a1/a2
// MFMAs still run (trans-pipe tail overlapped with matrix pipe). setprio spans
// MFMA+tanh so no scheduling fence splits them.

#define FM(T, K, ACC) ACC = __builtin_amdgcn_mfma_f32_16x16x32_bf16(w[T][K], bf[K], ACC, 0, 0, 0)
#define TST(ACC, IDX, COND) do { s4v hv_;                                  \
        _Pragma("unroll")                                                  \
        for (int r_ = 0; r_ < 4; ++r_) hv_[r_] = f2b(fast_tanh(ACC[r_]));  \
        if (COND) *(s4v*)&lds[IDX] = hv_; } while (0)

__global__ __launch_bounds__(512, 2)
void rnn_kernel(const float* __restrict__ x, const float* __restrict__ h0,
                const float* __restrict__ Wi, const float* __restrict__ Wh,
                const float* __restrict__ Wo, float* __restrict__ out)
{
    __shared__ short lds[2 * BUFS];
    const int tid  = threadIdx.x;
    const int lane = tid & 63;
    const int wv   = tid >> 6;          // wave 0..7
    const int l15  = lane & 15;
    const int lkhi = lane >> 4;         // k-subchunk 0..3 / n_local quad
    const int b0   = blockIdx.x * MT;
    const bool w3  = (wv < 3);          // third tile (t = wv+16 <= 18) real
    const bool t18mask = (wv != 2) || (lkhi != 3);  // tile-18 n>=300 lanes masked

    // ---- weight-stationary A-fragments: packed K (Wh k<300 | Wi k>=300) ----
    s8v w[NT][KF];
#pragma unroll
    for (int i = 0; i < NT; ++i) {
        const int n = (wv + 8 * i) * 16 + l15;
#pragma unroll
        for (int kf = 0; kf < KF; ++kf) {
            s8v v;
#pragma unroll
            for (int j = 0; j < 8; ++j) {
                int k = kf * 32 + lkhi * 8 + j;
                float f = 0.f;
                if (n < HIDDEN) f = (k < XK) ? Wh[n * HIDDEN + k] : Wi[n * IN_DIM + (k - XK)];
                v[j] = f2b(f);
            }
            w[i][kf] = v;
        }
    }

    // ---- zero both buffers ----
    {
        s4v z = (s4v){0, 0, 0, 0};
        for (int i = tid; i < 2 * BUFS / 4; i += 512)
            ((s4v*)lds)[i] = z;
    }
    __syncthreads();

    // ---- h0 -> buf0, frame-0 x -> buf0 ----
    for (int i = tid; i < MT * HIDDEN; i += 512) {
        int r = i / HIDDEN, c = i % HIDDEN;
        lds[g(r, c)] = f2b(h0[(size_t)(b0 + r) * HIDDEN + c]);
    }
    if (tid < 336) {
        const float4* xs = reinterpret_cast<const float4*>(x + (size_t)b0 * IN_DIM);
        float4 v0 = xs[tid];
        int r = tid / 21, c4 = (tid % 21) * 4;
        s4v pk = {f2b(v0.x), f2b(v0.y), f2b(v0.z), f2b(v0.w)};
        *reinterpret_cast<s4v*>(&lds[g(r, XK + c4)]) = pk;
    }

    // ---- per-lane constant bases (shorts) ----
    const int rdh   = g(l15, lkhi * 8);            // B-frag read base (+kf*32)
    const int wrb   = g(l15, lkhi * 4);            // h' write base (+t*16)
    const int xti   = (tid < 336) ? tid : 0;       // clamped x-load lane index
    const int xcb1  = g(xti / 21, XK + (xti % 21) * 4);
    const bool xact = (tid < 336);
    const f4v zero4 = (f4v){0.f, 0.f, 0.f, 0.f};   // persistent C=0

    // frame-1 preload
    float4 xa0, xb0;
    xa0 = reinterpret_cast<const float4*>(x + ((size_t)BATCH + b0) * IN_DIM)[xti];
    __syncthreads();

    // STEP: LOADF -> load frame SF+2 into B; COMMITF -> commit A (frame SF+1)
#define STEP(PH, SF, A0, B0, LOADF, COMMITF)                                    \
    {                                                                           \
        if (LOADF) {                                                            \
            B0 = reinterpret_cast<const float4*>(                               \
                x + ((size_t)((SF) + 2) * BATCH + b0) * IN_DIM)[xti];           \
        }                                                                       \
        if ((COMMITF) && xact) {   /* early: independent of this step's acc */  \
            s4v pk = {f2b(A0.x), f2b(A0.y), f2b(A0.z), f2b(A0.w)};              \
            *(s4v*)&lds[((PH) ^ 1) * BUFS + xcb1] = pk;                         \
        }                                                                       \
        s8v bf[KF];                                                             \
        _Pragma("unroll")                                                       \
        for (int kf = 0; kf < KF; ++kf)                                         \
            bf[kf] = *(const s8v*)&lds[(PH) * BUFS + rdh + kf * 32];            \
        __builtin_amdgcn_s_setprio(1);                                          \
        if (w3) {                                                               \
            f4v a0 = __builtin_amdgcn_mfma_f32_16x16x32_bf16(w[0][0], bf[0], zero4, 0, 0, 0); \
            FM(0, 1, a0); FM(0, 2, a0); FM(0, 3, a0);                           \
            f4v a1 = __builtin_amdgcn_mfma_f32_16x16x32_bf16(w[1][0], bf[0], zero4, 0, 0, 0); \
            FM(0, 4, a0); FM(1, 1, a1); FM(0, 5, a0); FM(1, 2, a1);             \
            FM(0, 6, a0); FM(1, 3, a1); FM(0, 7, a0);                           \
            f4v a2 = __builtin_amdgcn_mfma_f32_16x16x32_bf16(w[2][0], bf[0], zero4, 0, 0, 0); \
            FM(0, 8, a0); FM(1, 4, a1); FM(2, 1, a2);                           \
            FM(0, 9, a0); FM(1, 5, a1); FM(2, 2, a2);                           \
            FM(0, 10, a0); FM(1, 6, a1); FM(2, 3, a2);                          \
            FM(0, 11, a0);                                                      \
            TST(a0, ((PH) ^ 1) * BUFS + wrb + (wv) * 16, true);                 \
            FM(1, 7, a1); FM(2, 4, a2); FM(1, 8, a1); FM(2, 5, a2);             \
            FM(1, 9, a1); FM(2, 6, a2); FM(1, 10, a1); FM(2, 7, a2);            \
            FM(1, 11, a1);                                                      \
            TST(a1, ((PH) ^ 1) * BUFS + wrb + (wv + 8) * 16, true);             \
            FM(2, 8, a2); FM(2, 9, a2); FM(2, 10, a2); FM(2, 11, a2);           \
            TST(a2, ((PH) ^ 1) * BUFS + wrb + (wv + 16) * 16, t18mask);         \
        } else {                                                                \
            f4v a0 = __builtin_amdgcn_mfma_f32_16x16x32_bf16(w[0][0], bf[0], zero4, 0, 0, 0); \
            FM(0, 1, a0); FM(0, 2, a0); FM(0, 3, a0); FM(0, 4, a0); FM(0, 5, a0); \
            f4v a1 = __builtin_amdgcn_mfma_f32_16x16x32_bf16(w[1][0], bf[0], zero4, 0, 0, 0); \
            FM(0, 6, a0); FM(1, 1, a1); FM(0, 7, a0); FM(1, 2, a1);             \
            FM(0, 8, a0); FM(1, 3, a1); FM(0, 9, a0); FM(1, 4, a1);             \
            FM(0, 10, a0); FM(1, 5, a1); FM(0, 11, a0);                         \
            TST(a0, ((PH) ^ 1) * BUFS + wrb + (wv) * 16, true);                 \
            FM(1, 6, a1); FM(1, 7, a1); FM(1, 8, a1); FM(1, 9, a1);             \
            FM(1, 10, a1); FM(1, 11, a1);                                       \
            TST(a1, ((PH) ^ 1) * BUFS + wrb + (wv + 8) * 16, true);             \
        }                                                                       \
        __builtin_amdgcn_s_setprio(0);                                          \
        lgkm_barrier();                                                         \
    }

    // steps 0..509: always load+commit (SF+2 <= 511)
    for (int s = 0; s < FRAMES - 2; s += 2) {
        STEP(0, s,     xa0, xb0, 1, 1)
        STEP(1, s + 1, xb0, xa0, 1, 1)
    }
    // step 510 (PH0): commit frame 511 (in xa0), no load
    STEP(0, 510, xa0, xb0, 0, 1)
    // step 511 (PH1): no commit, no load
    STEP(1, 511, xb0, xa0, 0, 0)
#undef STEP

    // ---- epilogue: final h in buf0 (FRAMES even) ----
    float* hout = out + BATCH * OUT_DIM;
    for (int i = tid; i < MT * HIDDEN; i += 512) {
        int r = i / HIDDEN, c = i % HIDDEN;
        hout[(size_t)(b0 + r) * HIDDEN + c] = b2f(lds[g(r, c)]);
    }
    if (tid < MT * OUT_DIM) {
        int r = tid / OUT_DIM, c = tid % OUT_DIM;
        float sum = 0.f;
        for (int k = 0; k < HIDDEN; ++k)
            sum = fmaf(b2f(lds[g(r, k)]), Wo[c * HIDDEN + k], sum);
        out[(b0 + r) * OUT_DIM + c] = sum;
    }
}

extern "C" void kernel_launch(void* const* d_in, const int* in_sizes, int n_in,
                              void* d_out, int out_size, void* d_ws, size_t ws_size,
                              hipStream_t stream) {
    const float* x  = (const float*)d_in[0];
    const float* h0 = (const float*)d_in[1];
    const float* Wi = (const float*)d_in[2];
    const float* Wh = (const float*)d_in[3];
    const float* Wo = (const float*)d_in[4];
    float* out = (float*)d_out;
    rnn_kernel<<<dim3(BATCH / MT), dim3(512), 0, stream>>>(x, h0, Wi, Wh, Wo, out);
}

// Round 12
// 520.485 us; speedup vs baseline: 1.2347x; 1.0199x over previous
//
#include <hip/hip_runtime.h>
#include <hip/hip_bf16.h>

#define FRAMES 512
#define BATCH 2048
#define IN_DIM 84
#define HIDDEN 300
#define OUT_DIM 10

#define MT 16            // batch rows per workgroup
#define HROW 512         // bytes per h row (i8 data 0..319, swizzle pad)
#define XOFF 8192        // x region byte offset within a buffer
#define XROW 512         // bytes per x row (bf16 data 168B + swizzle pad)
#define BUFB 16384       // bytes per buffer
#define KFH 5            // i8 h-fragments (K=64 each: k 0..319, 300 real)
#define KFX 3            // bf16 x-fragments (K=32 each: k 0..95, 84 real)
#define NT 3             // tiles per wave: t = wv, wv+8, wv+16

typedef __attribute__((ext_vector_type(8))) short s8v;
typedef __attribute__((ext_vector_type(4))) short s4v;
typedef __attribute__((ext_vector_type(4))) float f4v;
typedef __attribute__((ext_vector_type(4))) int   i4v;

__device__ __forceinline__ short f2b(float x) {
    __hip_bfloat16 h = __float2bfloat16(x);
    return *reinterpret_cast<short*>(&h);
}
__device__ __forceinline__ float fast_tanh(float z) {
    float ex = __builtin_amdgcn_exp2f(z * 2.88539008177792681f); // exp(2z)
    return fmaf(-2.f, __builtin_amdgcn_rcpf(ex + 1.f), 1.f);
}
__device__ __forceinline__ void lgkm_barrier() {   // no vmcnt drain at barrier
    asm volatile("s_waitcnt lgkmcnt(0)" ::: "memory");
    __builtin_amdgcn_s_barrier();
}

// Swapped-operand step:  pre[n][b] = qs * (i8dot: Wh_q . h_q) + (bf16: Wi . x)
//   h as i8 (scale 1/127, exact range [-1,1]); Wh as i8 (global-max scale);
//   x and Wi stay bf16 (x unbounded -> i8 would blow the error budget).
//   h-part: mfma_i32_16x16x64_i8, 5 frags; x-part: mfma_f32_16x16x32_bf16, 3.
//   C/D (dtype-independent): lane l holds b = l&15, n = t*16 + (l>>4)*4 + r.
//   h' write = ONE ds_write_b32 (4 i8) per tile. Tile 18 lanes n>=300 masked.

#define MFI(T, K, ACC) ACC = __builtin_amdgcn_mfma_i32_16x16x64_i8(wq[T][K], bh[K], ACC, 0, 0, 0)
#define MFX(T, K, ACC) ACC = __builtin_amdgcn_mfma_f32_16x16x32_bf16(wx[T][K], bx[K], ACC, 0, 0, 0)
#define TAIL(AI, AF, IDX, COND) do { unsigned pk_ = 0;                          \
        _Pragma("unroll")                                                       \
        for (int r_ = 0; r_ < 4; ++r_) {                                        \
            float pre_ = fmaf(qs, (float)AI[r_], AF[r_]);                       \
            float t_ = fast_tanh(pre_);                                         \
            pk_ |= (__float_as_uint(fmaf(t_, 127.f, 12582912.f)) & 255u) << (8 * r_); \
        }                                                                       \
        if (COND) *(unsigned*)&ldsb[IDX] = pk_; } while (0)

__global__ __launch_bounds__(512, 2)
void rnn_kernel(const float* __restrict__ x, const float* __restrict__ h0,
                const float* __restrict__ Wi, const float* __restrict__ Wh,
                const float* __restrict__ Wo, float* __restrict__ out)
{
    __shared__ __align__(16) char ldsb[2 * BUFB];
    __shared__ float redbuf[8];
    const int tid  = threadIdx.x;
    const int lane = tid & 63;
    const int wv   = tid >> 6;          // wave 0..7
    const int l15  = lane & 15;
    const int lkhi = lane >> 4;
    const int b0   = blockIdx.x * MT;
    const bool w3  = (wv < 3);
    const bool t18mask = (wv != 2) || (lkhi != 3);

    // ---- deterministic global max|Wh| (identical in every WG) ----
    float m = 0.f;
    for (int i = tid; i < HIDDEN * HIDDEN; i += 512)
        m = fmaxf(m, fabsf(Wh[i]));
#pragma unroll
    for (int o = 32; o; o >>= 1) m = fmaxf(m, __shfl_xor(m, o));
    if (lane == 0) redbuf[wv] = m;
    __syncthreads();
    float gm = 0.f;
#pragma unroll
    for (int i = 0; i < 8; ++i) gm = fmaxf(gm, redbuf[i]);
    const float inv_sw = 127.f / gm;           // Wh -> q
    const float qs     = gm / (127.f * 127.f); // dequant of i32 dot (s_w * s_h)

    // ---- weight-stationary fragments: i8 Wh + bf16 Wi ----
    i4v wq[NT][KFH];
    s8v wx[NT][KFX];
#pragma unroll
    for (int i = 0; i < NT; ++i) {
        const int n = (wv + 8 * i) * 16 + l15;
#pragma unroll
        for (int kf = 0; kf < KFH; ++kf) {
            int dw0 = 0, dw1 = 0, dw2 = 0, dw3 = 0;
#pragma unroll
            for (int j = 0; j < 16; ++j) {
                int k = kf * 64 + lkhi * 16 + j;
                float f = (n < HIDDEN && k < HIDDEN) ? Wh[n * HIDDEN + k] : 0.f;
                int q = (int)rintf(f * inv_sw) & 255;
                if ((j >> 2) == 0) dw0 |= q << ((j & 3) * 8);
                else if ((j >> 2) == 1) dw1 |= q << ((j & 3) * 8);
                else if ((j >> 2) == 2) dw2 |= q << ((j & 3) * 8);
                else dw3 |= q << ((j & 3) * 8);
            }
            wq[i][kf] = (i4v){dw0, dw1, dw2, dw3};
        }
#pragma unroll
        for (int f = 0; f < KFX; ++f) {
            s8v v;
#pragma unroll
            for (int j = 0; j < 8; ++j) {
                int k = f * 32 + lkhi * 8 + j;
                v[j] = f2b((n < HIDDEN && k < IN_DIM) ? Wi[n * IN_DIM + k] : 0.f);
            }
            wx[i][f] = v;
        }
    }

    // ---- zero both buffers (all pads must be 0) ----
    {
        i4v z = (i4v){0, 0, 0, 0};
        for (int i = tid; i < 2 * BUFB / 16; i += 512)
            ((i4v*)ldsb)[i] = z;
    }
    __syncthreads();

    // ---- h0 (quantized) -> buf0, frame-0 x (bf16) -> buf0 ----
    for (int i = tid; i < MT * HIDDEN; i += 512) {
        int r = i / HIDDEN, c = i % HIDDEN;
        float h = h0[(size_t)(b0 + r) * HIDDEN + c];
        ldsb[r * HROW + ((r & 7) << 4) + c] =
            (char)(__float_as_uint(fmaf(h, 127.f, 12582912.f)) & 255u);
    }
    if (tid < 336) {
        const float4* xs = reinterpret_cast<const float4*>(x + (size_t)b0 * IN_DIM);
        float4 v0 = xs[tid];
        int r = tid / 21, c = tid % 21;
        s4v pk = {f2b(v0.x), f2b(v0.y), f2b(v0.z), f2b(v0.w)};
        *reinterpret_cast<s4v*>(&ldsb[XOFF + r * XROW + ((r & 7) << 4) + c * 8]) = pk;
    }

    // ---- per-lane constant byte bases ----
    const int hrd = l15 * HROW + ((l15 & 7) << 4) + lkhi * 16;   // + kf*64
    const int hwr = l15 * HROW + ((l15 & 7) << 4) + lkhi * 4;    // + t*16
    const int xrd = XOFF + l15 * XROW + ((l15 & 7) << 4) + lkhi * 16; // + f*64
    const int xti = (tid < 336) ? tid : 0;
    const int xr_ = xti / 21, xc_ = xti % 21;
    const int xcb = XOFF + xr_ * XROW + ((xr_ & 7) << 4) + xc_ * 8;
    const bool xact = (tid < 336);
    const f4v zero4 = (f4v){0.f, 0.f, 0.f, 0.f};
    const i4v zeroi = (i4v){0, 0, 0, 0};

    // frame-1 preload
    float4 xa0, xb0;
    xa0 = reinterpret_cast<const float4*>(x + ((size_t)BATCH + b0) * IN_DIM)[xti];
    __syncthreads();

#define STEP(PH, SF, A0, B0, LOADF, COMMITF)                                    \
    {                                                                           \
        if (LOADF) {                                                            \
            B0 = reinterpret_cast<const float4*>(                               \
                x + ((size_t)((SF) + 2) * BATCH + b0) * IN_DIM)[xti];           \
        }                                                                       \
        if ((COMMITF) && xact) {                                                \
            s4v pk = {f2b(A0.x), f2b(A0.y), f2b(A0.z), f2b(A0.w)};              \
            *(s4v*)&ldsb[((PH) ^ 1) * BUFB + xcb] = pk;                         \
        }                                                                       \
        i4v bh[KFH]; s8v bx[KFX];                                               \
        _Pragma("unroll")                                                       \
        for (int kf = 0; kf < KFH; ++kf)                                        \
            bh[kf] = *(const i4v*)&ldsb[(PH) * BUFB + hrd + kf * 64];           \
        _Pragma("unroll")                                                       \
        for (int f = 0; f < KFX; ++f)                                           \
            bx[f] = *(const s8v*)&ldsb[(PH) * BUFB + xrd + f * 64];             \
        __builtin_amdgcn_s_setprio(1);                                          \
        if (w3) {                                                               \
            i4v a0i = __builtin_amdgcn_mfma_i32_16x16x64_i8(wq[0][0], bh[0], zeroi, 0, 0, 0); \
            i4v a1i = __builtin_amdgcn_mfma_i32_16x16x64_i8(wq[1][0], bh[0], zeroi, 0, 0, 0); \
            i4v a2i = __builtin_amdgcn_mfma_i32_16x16x64_i8(wq[2][0], bh[0], zeroi, 0, 0, 0); \
            _Pragma("unroll")                                                   \
            for (int kf = 1; kf < KFH; ++kf) {                                  \
                MFI(0, kf, a0i); MFI(1, kf, a1i); MFI(2, kf, a2i);              \
            }                                                                   \
            f4v a0f = __builtin_amdgcn_mfma_f32_16x16x32_bf16(wx[0][0], bx[0], zero4, 0, 0, 0); \
            f4v a1f = __builtin_amdgcn_mfma_f32_16x16x32_bf16(wx[1][0], bx[0], zero4, 0, 0, 0); \
            f4v a2f = __builtin_amdgcn_mfma_f32_16x16x32_bf16(wx[2][0], bx[0], zero4, 0, 0, 0); \
            _Pragma("unroll")                                                   \
            for (int f = 1; f < KFX; ++f) {                                     \
                MFX(0, f, a0f); MFX(1, f, a1f); MFX(2, f, a2f);                 \
            }                                                                   \
            __builtin_amdgcn_s_setprio(0);                                      \
            TAIL(a0i, a0f, ((PH) ^ 1) * BUFB + hwr + (wv) * 16, true);          \
            TAIL(a1i, a1f, ((PH) ^ 1) * BUFB + hwr + (wv + 8) * 16, true);      \
            TAIL(a2i, a2f, ((PH) ^ 1) * BUFB + hwr + (wv + 16) * 16, t18mask);  \
        } else {                                                                \
            i4v a0i = __builtin_amdgcn_mfma_i32_16x16x64_i8(wq[0][0], bh[0], zeroi, 0, 0, 0); \
            i4v a1i = __builtin_amdgcn_mfma_i32_16x16x64_i8(wq[1][0], bh[0], zeroi, 0, 0, 0); \
            _Pragma("unroll")                                                   \
            for (int kf = 1; kf < KFH; ++kf) {                                  \
                MFI(0, kf, a0i); MFI(1, kf, a1i);                               \
            }                                                                   \
            f4v a0f = __builtin_amdgcn_mfma_f32_16x16x32_bf16(wx[0][0], bx[0], zero4, 0, 0, 0); \
            f4v a1f = __builtin_amdgcn_mfma_f32_16x16x32_bf16(wx[1][0], bx[0], zero4, 0, 0, 0); \
            _Pragma("unroll")                                                   \
            for (int f = 1; f < KFX; ++f) {                                     \
                MFX(0, f, a0f); MFX(1, f, a1f);                                 \
            }                                                                   \
            __builtin_amdgcn_s_setprio(0);                                      \
            TAIL(a0i, a0f, ((PH) ^ 1) * BUFB + hwr + (wv) * 16, true);          \
            TAIL(a1i, a1f, ((PH) ^ 1) * BUFB + hwr + (wv + 8) * 16, true);      \
        }                                                                       \
        lgkm_barrier();                                                         \
    }

    for (int s = 0; s < FRAMES - 2; s += 2) {
        STEP(0, s,     xa0, xb0, 1, 1)
        STEP(1, s + 1, xb0, xa0, 1, 1)
    }
    STEP(0, 510, xa0, xb0, 0, 1)
    STEP(1, 511, xb0, xa0, 0, 0)
#undef STEP

    // ---- epilogue: final h (i8, buf0 since FRAMES even) -> f32 ----
    const float dq = 1.f / 127.f;
    float* hout = out + BATCH * OUT_DIM;
    for (int i = tid; i < MT * HIDDEN; i += 512) {
        int r = i / HIDDEN, c = i % HIDDEN;
        hout[(size_t)(b0 + r) * HIDDEN + c] =
            (float)((int)(signed char)ldsb[r * HROW + ((r & 7) << 4) + c]) * dq;
    }
    if (tid < MT * OUT_DIM) {
        int r = tid / OUT_DIM, c = tid % OUT_DIM;
        float sum = 0.f;
        for (int k = 0; k < HIDDEN; ++k) {
            float h = (float)((int)(signed char)ldsb[r * HROW + ((r & 7) << 4) + k]) * dq;
            sum = fmaf(h, Wo[c * HIDDEN + k], sum);
        }
        out[(b0 + r) * OUT_DIM + c] = sum;
    }
}

extern "C" void kernel_launch(void* const* d_in, const int* in_sizes, int n_in,
                              void* d_out, int out_size, void* d_ws, size_t ws_size,
                              hipStream_t stream) {
    const float* x  = (const float*)d_in[0];
    const float* h0 = (const float*)d_in[1];
    const float* Wi = (const float*)d_in[2];
    const float* Wh = (const float*)d_in[3];
    const float* Wo = (const float*)d_in[4];
    float* out = (float*)d_out;
    rnn_kernel<<<dim3(BATCH / MT), dim3(512), 0, stream>>>(x, h0, Wi, Wh, Wo, out);
}

// Round 13
// 474.997 us; speedup vs baseline: 1.3529x; 1.0958x over previous
//
#include <hip/hip_runtime.h>
#include <hip/hip_bf16.h>

#define FRAMES 512
#define BATCH 2048
#define IN_DIM 84
#define HIDDEN 300
#define OUT_DIM 10

#define MT 16            // batch rows per workgroup
#define HROW 512         // bytes per h row (i8 data 0..319, swizzle pad)
#define XOFF 8192        // x region byte offset within a buffer
#define XROW 512         // bytes per x row (bf16 data 168B + swizzle pad)
#define BUFB 16384       // bytes per buffer
#define KFH 5            // i8 h-fragments (K=64 each: k 0..319, 300 real)
#define KFX 3            // bf16 x-fragments (K=32 each: k 0..95, 84 real)
#define NT 3             // tiles per wave: t = wv, wv+8, wv+16

#define L2E2 2.88539008177792681f   // 2*log2(e), folded into Wi and qs

typedef __attribute__((ext_vector_type(8))) short s8v;
typedef __attribute__((ext_vector_type(4))) short s4v;
typedef __attribute__((ext_vector_type(4))) float f4v;
typedef __attribute__((ext_vector_type(4))) int   i4v;

__device__ __forceinline__ short f2b(float x) {
    __hip_bfloat16 h = __float2bfloat16(x);
    return *reinterpret_cast<short*>(&h);
}
__device__ __forceinline__ void lgkm_barrier() {   // no vmcnt drain at barrier
    asm volatile("s_waitcnt lgkmcnt(0)" ::: "memory");
    __builtin_amdgcn_s_barrier();
}

// Swapped-operand step:  pre[n][b] = qs*(i8dot: Wh_q . h_q) + (bf16: (c*Wi) . x)
//   tanh+quant tail fully fused:  z2 = fma(qs*c, AI, AFx)  (c = 2*log2 e)
//   ex = exp2(z2);  q_byte = fma(-254, rcp(ex+1), 127 + 1.5*2^23)  [magic-add RNE]
//   pack 4 bytes via v_perm_b32 x3.  h' write = ONE ds_write_b32 per tile.
//   Tile 18's n=300..303 lands in zero-weighted h-pad -> no mask needed.

#define MFI(T, K, ACC) ACC = __builtin_amdgcn_mfma_i32_16x16x64_i8(wq[T][K], bh[K], ACC, 0, 0, 0)
#define MFX(T, K, ACC) ACC = __builtin_amdgcn_mfma_f32_16x16x32_bf16(wx[T][K], bx[K], ACC, 0, 0, 0)
#define TAIL(AI, AF, IDX) do { unsigned b_[4];                                  \
        _Pragma("unroll")                                                       \
        for (int r_ = 0; r_ < 4; ++r_) {                                        \
            float z2_ = fmaf(qs2885, (float)AI[r_], AF[r_]);                    \
            float ex_ = __builtin_amdgcn_exp2f(z2_);                            \
            b_[r_] = __float_as_uint(                                           \
                fmaf(-254.f, __builtin_amdgcn_rcpf(ex_ + 1.f), 12583039.f));    \
        }                                                                       \
        unsigned t0_ = __builtin_amdgcn_perm(b_[1], b_[0], 0x00000400u);        \
        unsigned t1_ = __builtin_amdgcn_perm(b_[3], b_[2], 0x00000400u);        \
        unsigned pk_ = __builtin_amdgcn_perm(t1_, t0_, 0x05040100u);            \
        *(unsigned*)&ldsb[IDX] = pk_; } while (0)

__global__ __launch_bounds__(512, 2)
void rnn_kernel(const float* __restrict__ x, const float* __restrict__ h0,
                const float* __restrict__ Wi, const float* __restrict__ Wh,
                const float* __restrict__ Wo, float* __restrict__ out)
{
    __shared__ __align__(16) char ldsb[2 * BUFB];
    __shared__ float redbuf[8];
    const int tid  = threadIdx.x;
    const int lane = tid & 63;
    const int wv   = tid >> 6;          // wave 0..7
    const int l15  = lane & 15;
    const int lkhi = lane >> 4;
    const int b0   = blockIdx.x * MT;
    const bool w3  = (wv < 3);

    // ---- deterministic global max|Wh| (identical in every WG) ----
    float m = 0.f;
    for (int i = tid; i < HIDDEN * HIDDEN; i += 512)
        m = fmaxf(m, fabsf(Wh[i]));
#pragma unroll
    for (int o = 32; o; o >>= 1) m = fmaxf(m, __shfl_xor(m, o));
    if (lane == 0) redbuf[wv] = m;
    __syncthreads();
    float gm = 0.f;
#pragma unroll
    for (int i = 0; i < 8; ++i) gm = fmaxf(gm, redbuf[i]);
    const float inv_sw = 127.f / gm;                    // Wh -> q
    const float qs2885 = (gm / (127.f * 127.f)) * L2E2; // dequant * 2log2e fused

    // ---- weight-stationary fragments: i8 Wh + bf16 (L2E2 * Wi) ----
    i4v wq[NT][KFH];
    s8v wx[NT][KFX];
#pragma unroll
    for (int i = 0; i < NT; ++i) {
        const int n = (wv + 8 * i) * 16 + l15;
#pragma unroll
        for (int kf = 0; kf < KFH; ++kf) {
            int dw0 = 0, dw1 = 0, dw2 = 0, dw3 = 0;
#pragma unroll
            for (int j = 0; j < 16; ++j) {
                int k = kf * 64 + lkhi * 16 + j;
                float f = (n < HIDDEN && k < HIDDEN) ? Wh[n * HIDDEN + k] : 0.f;
                int q = (int)rintf(f * inv_sw) & 255;
                if ((j >> 2) == 0) dw0 |= q << ((j & 3) * 8);
                else if ((j >> 2) == 1) dw1 |= q << ((j & 3) * 8);
                else if ((j >> 2) == 2) dw2 |= q << ((j & 3) * 8);
                else dw3 |= q << ((j & 3) * 8);
            }
            wq[i][kf] = (i4v){dw0, dw1, dw2, dw3};
        }
#pragma unroll
        for (int f = 0; f < KFX; ++f) {
            s8v v;
#pragma unroll
            for (int j = 0; j < 8; ++j) {
                int k = f * 32 + lkhi * 8 + j;
                v[j] = f2b((n < HIDDEN && k < IN_DIM) ? L2E2 * Wi[n * IN_DIM + k] : 0.f);
            }
            wx[i][f] = v;
        }
    }

    // ---- zero both buffers (all pads must be 0) ----
    {
        i4v z = (i4v){0, 0, 0, 0};
        for (int i = tid; i < 2 * BUFB / 16; i += 512)
            ((i4v*)ldsb)[i] = z;
    }
    __syncthreads();

    // ---- h0 (quantized) -> buf0, frame-0 x (bf16) -> buf0 ----
    for (int i = tid; i < MT * HIDDEN; i += 512) {
        int r = i / HIDDEN, c = i % HIDDEN;
        float h = h0[(size_t)(b0 + r) * HIDDEN + c];
        ldsb[r * HROW + ((r & 7) << 4) + c] =
            (char)(__float_as_uint(fmaf(h, 127.f, 12582912.f)) & 255u);
    }
    if (tid < 336) {
        const float4* xs = reinterpret_cast<const float4*>(x + (size_t)b0 * IN_DIM);
        float4 v0 = xs[tid];
        int r = tid / 21, c = tid % 21;
        s4v pk = {f2b(v0.x), f2b(v0.y), f2b(v0.z), f2b(v0.w)};
        *reinterpret_cast<s4v*>(&ldsb[XOFF + r * XROW + ((r & 7) << 4) + c * 8]) = pk;
    }

    // ---- per-lane constant byte bases ----
    const int hrd = l15 * HROW + ((l15 & 7) << 4) + lkhi * 16;   // + kf*64
    const int hwr = l15 * HROW + ((l15 & 7) << 4) + lkhi * 4;    // + t*16
    const int xrd = XOFF + l15 * XROW + ((l15 & 7) << 4) + lkhi * 16; // + f*64
    const int xti = (tid < 336) ? tid : 0;
    const int xr_ = xti / 21, xc_ = xti % 21;
    const int xcb = XOFF + xr_ * XROW + ((xr_ & 7) << 4) + xc_ * 8;
    const bool xact = (tid < 336);
    const f4v zero4 = (f4v){0.f, 0.f, 0.f, 0.f};
    const i4v zeroi = (i4v){0, 0, 0, 0};

    // frame-1 preload
    float4 xa0, xb0;
    xa0 = reinterpret_cast<const float4*>(x + ((size_t)BATCH + b0) * IN_DIM)[xti];
    __syncthreads();

#define STEP(PH, SF, A0, B0, LOADF, COMMITF)                                    \
    {                                                                           \
        if (LOADF) {                                                            \
            B0 = reinterpret_cast<const float4*>(                               \
                x + ((size_t)((SF) + 2) * BATCH + b0) * IN_DIM)[xti];           \
        }                                                                       \
        if ((COMMITF) && xact) {                                                \
            s4v pk = {f2b(A0.x), f2b(A0.y), f2b(A0.z), f2b(A0.w)};              \
            *(s4v*)&ldsb[((PH) ^ 1) * BUFB + xcb] = pk;                         \
        }                                                                       \
        i4v bh[KFH]; s8v bx[KFX];                                               \
        _Pragma("unroll")                                                       \
        for (int kf = 0; kf < KFH; ++kf)                                        \
            bh[kf] = *(const i4v*)&ldsb[(PH) * BUFB + hrd + kf * 64];           \
        _Pragma("unroll")                                                       \
        for (int f = 0; f < KFX; ++f)                                           \
            bx[f] = *(const s8v*)&ldsb[(PH) * BUFB + xrd + f * 64];             \
        __builtin_amdgcn_s_setprio(1);                                          \
        if (w3) {                                                               \
            i4v a0i = __builtin_amdgcn_mfma_i32_16x16x64_i8(wq[0][0], bh[0], zeroi, 0, 0, 0); \
            i4v a1i = __builtin_amdgcn_mfma_i32_16x16x64_i8(wq[1][0], bh[0], zeroi, 0, 0, 0); \
            i4v a2i = __builtin_amdgcn_mfma_i32_16x16x64_i8(wq[2][0], bh[0], zeroi, 0, 0, 0); \
            _Pragma("unroll")                                                   \
            for (int kf = 1; kf < KFH; ++kf) {                                  \
                MFI(0, kf, a0i); MFI(1, kf, a1i); MFI(2, kf, a2i);              \
            }                                                                   \
            f4v a0f = __builtin_amdgcn_mfma_f32_16x16x32_bf16(wx[0][0], bx[0], zero4, 0, 0, 0); \
            f4v a1f = __builtin_amdgcn_mfma_f32_16x16x32_bf16(wx[1][0], bx[0], zero4, 0, 0, 0); \
            f4v a2f = __builtin_amdgcn_mfma_f32_16x16x32_bf16(wx[2][0], bx[0], zero4, 0, 0, 0); \
            _Pragma("unroll")                                                   \
            for (int f = 1; f < KFX; ++f) {                                     \
                MFX(0, f, a0f); MFX(1, f, a1f); MFX(2, f, a2f);                 \
            }                                                                   \
            __builtin_amdgcn_s_setprio(0);                                      \
            TAIL(a0i, a0f, ((PH) ^ 1) * BUFB + hwr + (wv) * 16);                \
            TAIL(a1i, a1f, ((PH) ^ 1) * BUFB + hwr + (wv + 8) * 16);            \
            TAIL(a2i, a2f, ((PH) ^ 1) * BUFB + hwr + (wv + 16) * 16);           \
        } else {                                                                \
            i4v a0i = __builtin_amdgcn_mfma_i32_16x16x64_i8(wq[0][0], bh[0], zeroi, 0, 0, 0); \
            i4v a1i = __builtin_amdgcn_mfma_i32_16x16x64_i8(wq[1][0], bh[0], zeroi, 0, 0, 0); \
            _Pragma("unroll")                                                   \
            for (int kf = 1; kf < KFH; ++kf) {                                  \
                MFI(0, kf, a0i); MFI(1, kf, a1i);                               \
            }                                                                   \
            f4v a0f = __builtin_amdgcn_mfma_f32_16x16x32_bf16(wx[0][0], bx[0], zero4, 0, 0, 0); \
            f4v a1f = __builtin_amdgcn_mfma_f32_16x16x32_bf16(wx[1][0], bx[0], zero4, 0, 0, 0); \
            _Pragma("unroll")                                                   \
            for (int f = 1; f < KFX; ++f) {                                     \
                MFX(0, f, a0f); MFX(1, f, a1f);                                 \
            }                                                                   \
            __builtin_amdgcn_s_setprio(0);                                      \
            TAIL(a0i, a0f, ((PH) ^ 1) * BUFB + hwr + (wv) * 16);                \
            TAIL(a1i, a1f, ((PH) ^ 1) * BUFB + hwr + (wv + 8) * 16);            \
        }                                                                       \
        lgkm_barrier();                                                         \
    }

    for (int s = 0; s < FRAMES - 2; s += 2) {
        STEP(0, s,     xa0, xb0, 1, 1)
        STEP(1, s + 1, xb0, xa0, 1, 1)
    }
    STEP(0, 510, xa0, xb0, 0, 1)
    STEP(1, 511, xb0, xa0, 0, 0)
#undef STEP

    // ---- epilogue: final h (i8, buf0 since FRAMES even) -> f32 ----
    const float dq = 1.f / 127.f;
    float* hout = out + BATCH * OUT_DIM;
    for (int i = tid; i < MT * HIDDEN; i += 512) {
        int r = i / HIDDEN, c = i % HIDDEN;
        hout[(size_t)(b0 + r) * HIDDEN + c] =
            (float)((int)(signed char)ldsb[r * HROW + ((r & 7) << 4) + c]) * dq;
    }
    if (tid < MT * OUT_DIM) {
        int r = tid / OUT_DIM, c = tid % OUT_DIM;
        float sum = 0.f;
        for (int k = 0; k < HIDDEN; ++k) {
            float h = (float)((int)(signed char)ldsb[r * HROW + ((r & 7) << 4) + k]) * dq;
            sum = fmaf(h, Wo[c * HIDDEN + k], sum);
        }
        out[(b0 + r) * OUT_DIM + c] = sum;
    }
}

extern "C" void kernel_launch(void* const* d_in, const int* in_sizes, int n_in,
                              void* d_out, int out_size, void* d_ws, size_t ws_size,
                              hipStream_t stream) {
    const float* x  = (const float*)d_in[0];
    const float* h0 = (const float*)d_in[1];
    const float* Wi = (const float*)d_in[2];
    const float* Wh = (const float*)d_in[3];
    const float* Wo = (const float*)d_in[4];
    float* out = (float*)d_out;
    rnn_kernel<<<dim3(BATCH / MT), dim3(512), 0, stream>>>(x, h0, Wi, Wh, Wo, out);
}

// Round 14
// 445.093 us; speedup vs baseline: 1.4438x; 1.0672x over previous
//
#include <hip/hip_runtime.h>
#include <hip/hip_bf16.h>

#define FRAMES 512
#define BATCH 2048
#define IN_DIM 84
#define HIDDEN 300
#define OUT_DIM 10

#define MT 16            // batch rows per workgroup
#define HROW 512         // bytes per h row (i8 data 0..319, swizzle pad)
#define XOFF 8192        // x region byte offset within a buffer
#define XROW 512         // bytes per x row (bf16 data 168B + swizzle pad)
#define BUFB 16384       // bytes per buffer
#define KFH 5            // i8 h-fragments (K=64 each: k 0..319, 300 real)
#define KFX 3            // bf16 x-fragments (K=32 each: k 0..95, 84 real)
#define NT 3             // tiles per wave: t = wv, wv+8, wv+16
#define XBASE 176        // x-load/commit lanes tid in [176, 512): biases the
                         // commit work onto the 2-tile waves (3-tile waves gate the barrier)

#define L2E2 2.88539008177792681f   // 2*log2(e), folded into Wi and qs

typedef __attribute__((ext_vector_type(8))) short s8v;
typedef __attribute__((ext_vector_type(4))) short s4v;
typedef __attribute__((ext_vector_type(4))) float f4v;
typedef __attribute__((ext_vector_type(4))) int   i4v;

__device__ __forceinline__ short f2b(float x) {
    __hip_bfloat16 h = __float2bfloat16(x);
    return *reinterpret_cast<short*>(&h);
}
__device__ __forceinline__ void lgkm_barrier() {   // no vmcnt drain at barrier
    asm volatile("s_waitcnt lgkmcnt(0)" ::: "memory");
    __builtin_amdgcn_s_barrier();
}

// Swapped-operand step:  pre[n][b] = qs*(i8dot: Wh_q . h_q) + (bf16: (c*Wi) . x)
//   tanh+quant tail fully fused (see TAIL); h' write = ONE ds_write_b32 per tile.
//   x-commit via v_cvt_pk_bf16_f32 (2 instrs for 4 floats, no builtin on gfx950).

#define MFI(T, K, ACC) ACC = __builtin_amdgcn_mfma_i32_16x16x64_i8(wq[T][K], bh[K], ACC, 0, 0, 0)
#define MFX(T, K, ACC) ACC = __builtin_amdgcn_mfma_f32_16x16x32_bf16(wx[T][K], bx[K], ACC, 0, 0, 0)
#define TAIL(AI, AF, IDX) do { unsigned b_[4];                                  \
        _Pragma("unroll")                                                       \
        for (int r_ = 0; r_ < 4; ++r_) {                                        \
            float z2_ = fmaf(qs2885, (float)AI[r_], AF[r_]);                    \
            float ex_ = __builtin_amdgcn_exp2f(z2_);                            \
            b_[r_] = __float_as_uint(                                           \
                fmaf(-254.f, __builtin_amdgcn_rcpf(ex_ + 1.f), 12583039.f));    \
        }                                                                       \
        unsigned t0_ = __builtin_amdgcn_perm(b_[1], b_[0], 0x00000400u);        \
        unsigned t1_ = __builtin_amdgcn_perm(b_[3], b_[2], 0x00000400u);        \
        unsigned pk_ = __builtin_amdgcn_perm(t1_, t0_, 0x05040100u);            \
        *(unsigned*)&ldsb[IDX] = pk_; } while (0)

__global__ __launch_bounds__(512, 2)
void rnn_kernel(const float* __restrict__ x, const float* __restrict__ h0,
                const float* __restrict__ Wi, const float* __restrict__ Wh,
                const float* __restrict__ Wo, float* __restrict__ out)
{
    __shared__ __align__(16) char ldsb[2 * BUFB];
    __shared__ float redbuf[8];
    const int tid  = threadIdx.x;
    const int lane = tid & 63;
    const int wv   = tid >> 6;          // wave 0..7
    const int l15  = lane & 15;
    const int lkhi = lane >> 4;
    const int b0   = blockIdx.x * MT;
    const bool w3  = (wv < 3);

    // ---- deterministic global max|Wh| (identical in every WG) ----
    float m = 0.f;
    for (int i = tid; i < HIDDEN * HIDDEN; i += 512)
        m = fmaxf(m, fabsf(Wh[i]));
#pragma unroll
    for (int o = 32; o; o >>= 1) m = fmaxf(m, __shfl_xor(m, o));
    if (lane == 0) redbuf[wv] = m;
    __syncthreads();
    float gm = 0.f;
#pragma unroll
    for (int i = 0; i < 8; ++i) gm = fmaxf(gm, redbuf[i]);
    const float inv_sw = 127.f / gm;                    // Wh -> q
    const float qs2885 = (gm / (127.f * 127.f)) * L2E2; // dequant * 2log2e fused

    // ---- weight-stationary fragments: i8 Wh + bf16 (L2E2 * Wi) ----
    i4v wq[NT][KFH];
    s8v wx[NT][KFX];
#pragma unroll
    for (int i = 0; i < NT; ++i) {
        const int n = (wv + 8 * i) * 16 + l15;
#pragma unroll
        for (int kf = 0; kf < KFH; ++kf) {
            int dw0 = 0, dw1 = 0, dw2 = 0, dw3 = 0;
#pragma unroll
            for (int j = 0; j < 16; ++j) {
                int k = kf * 64 + lkhi * 16 + j;
                float f = (n < HIDDEN && k < HIDDEN) ? Wh[n * HIDDEN + k] : 0.f;
                int q = (int)rintf(f * inv_sw) & 255;
                if ((j >> 2) == 0) dw0 |= q << ((j & 3) * 8);
                else if ((j >> 2) == 1) dw1 |= q << ((j & 3) * 8);
                else if ((j >> 2) == 2) dw2 |= q << ((j & 3) * 8);
                else dw3 |= q << ((j & 3) * 8);
            }
            wq[i][kf] = (i4v){dw0, dw1, dw2, dw3};
        }
#pragma unroll
        for (int f = 0; f < KFX; ++f) {
            s8v v;
#pragma unroll
            for (int j = 0; j < 8; ++j) {
                int k = f * 32 + lkhi * 8 + j;
                v[j] = f2b((n < HIDDEN && k < IN_DIM) ? L2E2 * Wi[n * IN_DIM + k] : 0.f);
            }
            wx[i][f] = v;
        }
    }

    // ---- zero both buffers (all pads must be 0) ----
    {
        i4v z = (i4v){0, 0, 0, 0};
        for (int i = tid; i < 2 * BUFB / 16; i += 512)
            ((i4v*)ldsb)[i] = z;
    }
    __syncthreads();

    // ---- h0 (quantized) -> buf0, frame-0 x (bf16) -> buf0 ----
    for (int i = tid; i < MT * HIDDEN; i += 512) {
        int r = i / HIDDEN, c = i % HIDDEN;
        float h = h0[(size_t)(b0 + r) * HIDDEN + c];
        ldsb[r * HROW + ((r & 7) << 4) + c] =
            (char)(__float_as_uint(fmaf(h, 127.f, 12582912.f)) & 255u);
    }
    {
        const bool xa0_ = (tid >= XBASE);
        const int  xi0_ = xa0_ ? tid - XBASE : 0;
        if (xa0_) {
            const float4* xs = reinterpret_cast<const float4*>(x + (size_t)b0 * IN_DIM);
            float4 v0 = xs[xi0_];
            int r = xi0_ / 21, c = xi0_ % 21;
            s4v pk = {f2b(v0.x), f2b(v0.y), f2b(v0.z), f2b(v0.w)};
            *reinterpret_cast<s4v*>(&ldsb[XOFF + r * XROW + ((r & 7) << 4) + c * 8]) = pk;
        }
    }

    // ---- per-lane constant byte bases ----
    const int hrd = l15 * HROW + ((l15 & 7) << 4) + lkhi * 16;   // + kf*64
    const int hwr = l15 * HROW + ((l15 & 7) << 4) + lkhi * 4;    // + t*16
    const int xrd = XOFF + l15 * XROW + ((l15 & 7) << 4) + lkhi * 16; // + f*64
    const bool xact = (tid >= XBASE);
    const int  xi   = xact ? tid - XBASE : 0;       // 0..335 on active lanes
    const int  xr_  = xi / 21, xc_ = xi % 21;
    const int  xcb  = XOFF + xr_ * XROW + ((xr_ & 7) << 4) + xc_ * 8;
    const f4v zero4 = (f4v){0.f, 0.f, 0.f, 0.f};
    const i4v zeroi = (i4v){0, 0, 0, 0};

    // frame-1 preload
    float4 xa0, xb0;
    xa0 = reinterpret_cast<const float4*>(x + ((size_t)BATCH + b0) * IN_DIM)[xi];
    __syncthreads();

#define STEP(PH, SF, A0, B0, LOADF, COMMITF)                                    \
    {                                                                           \
        if (LOADF) {                                                            \
            B0 = reinterpret_cast<const float4*>(                               \
                x + ((size_t)((SF) + 2) * BATCH + b0) * IN_DIM)[xi];            \
        }                                                                       \
        if ((COMMITF) && xact) {                                                \
            unsigned d0_, d1_;                                                  \
            asm("v_cvt_pk_bf16_f32 %0, %1, %2" : "=v"(d0_) : "v"(A0.x), "v"(A0.y)); \
            asm("v_cvt_pk_bf16_f32 %0, %1, %2" : "=v"(d1_) : "v"(A0.z), "v"(A0.w)); \
            uint2 pk_; pk_.x = d0_; pk_.y = d1_;                                \
            *(uint2*)&ldsb[((PH) ^ 1) * BUFB + xcb] = pk_;                      \
        }                                                                       \
        i4v bh[KFH]; s8v bx[KFX];                                               \
        _Pragma("unroll")                                                       \
        for (int kf = 0; kf < KFH; ++kf)                                        \
            bh[kf] = *(const i4v*)&ldsb[(PH) * BUFB + hrd + kf * 64];           \
        _Pragma("unroll")                                                       \
        for (int f = 0; f < KFX; ++f)                                           \
            bx[f] = *(const s8v*)&ldsb[(PH) * BUFB + xrd + f * 64];             \
        __builtin_amdgcn_s_setprio(1);                                          \
        if (w3) {                                                               \
            i4v a0i = __builtin_amdgcn_mfma_i32_16x16x64_i8(wq[0][0], bh[0], zeroi, 0, 0, 0); \
            i4v a1i = __builtin_amdgcn_mfma_i32_16x16x64_i8(wq[1][0], bh[0], zeroi, 0, 0, 0); \
            i4v a2i = __builtin_amdgcn_mfma_i32_16x16x64_i8(wq[2][0], bh[0], zeroi, 0, 0, 0); \
            _Pragma("unroll")                                                   \
            for (int kf = 1; kf < KFH; ++kf) {                                  \
                MFI(0, kf, a0i); MFI(1, kf, a1i); MFI(2, kf, a2i);              \
            }                                                                   \
            f4v a0f = __builtin_amdgcn_mfma_f32_16x16x32_bf16(wx[0][0], bx[0], zero4, 0, 0, 0); \
            f4v a1f = __builtin_amdgcn_mfma_f32_16x16x32_bf16(wx[1][0], bx[0], zero4, 0, 0, 0); \
            f4v a2f = __builtin_amdgcn_mfma_f32_16x16x32_bf16(wx[2][0], bx[0], zero4, 0, 0, 0); \
            _Pragma("unroll")                                                   \
            for (int f = 1; f < KFX; ++f) {                                     \
                MFX(0, f, a0f); MFX(1, f, a1f); MFX(2, f, a2f);                 \
            }                                                                   \
            __builtin_amdgcn_s_setprio(0);                                      \
            TAIL(a0i, a0f, ((PH) ^ 1) * BUFB + hwr + (wv) * 16);                \
            TAIL(a1i, a1f, ((PH) ^ 1) * BUFB + hwr + (wv + 8) * 16);            \
            TAIL(a2i, a2f, ((PH) ^ 1) * BUFB + hwr + (wv + 16) * 16);           \
        } else {                                                                \
            i4v a0i = __builtin_amdgcn_mfma_i32_16x16x64_i8(wq[0][0], bh[0], zeroi, 0, 0, 0); \
            i4v a1i = __builtin_amdgcn_mfma_i32_16x16x64_i8(wq[1][0], bh[0], zeroi, 0, 0, 0); \
            _Pragma("unroll")                                                   \
            for (int kf = 1; kf < KFH; ++kf) {                                  \
                MFI(0, kf, a0i); MFI(1, kf, a1i);                               \
            }                                                                   \
            f4v a0f = __builtin_amdgcn_mfma_f32_16x16x32_bf16(wx[0][0], bx[0], zero4, 0, 0, 0); \
            f4v a1f = __builtin_amdgcn_mfma_f32_16x16x32_bf16(wx[1][0], bx[0], zero4, 0, 0, 0); \
            _Pragma("unroll")                                                   \
            for (int f = 1; f < KFX; ++f) {                                     \
                MFX(0, f, a0f); MFX(1, f, a1f);                                 \
            }                                                                   \
            __builtin_amdgcn_s_setprio(0);                                      \
            TAIL(a0i, a0f, ((PH) ^ 1) * BUFB + hwr + (wv) * 16);                \
            TAIL(a1i, a1f, ((PH) ^ 1) * BUFB + hwr + (wv + 8) * 16);            \
        }                                                                       \
        lgkm_barrier();                                                         \
    }

    for (int s = 0; s < FRAMES - 2; s += 2) {
        STEP(0, s,     xa0, xb0, 1, 1)
        STEP(1, s + 1, xb0, xa0, 1, 1)
    }
    STEP(0, 510, xa0, xb0, 0, 1)
    STEP(1, 511, xb0, xa0, 0, 0)
#undef STEP

    // ---- epilogue: final h (i8, buf0 since FRAMES even) -> f32 ----
    const float dq = 1.f / 127.f;
    float* hout = out + BATCH * OUT_DIM;
    for (int i = tid; i < MT * HIDDEN; i += 512) {
        int r = i / HIDDEN, c = i % HIDDEN;
        hout[(size_t)(b0 + r) * HIDDEN + c] =
            (float)((int)(signed char)ldsb[r * HROW + ((r & 7) << 4) + c]) * dq;
    }
    if (tid < MT * OUT_DIM) {
        int r = tid / OUT_DIM, c = tid % OUT_DIM;
        float sum = 0.f;
        for (int k = 0; k < HIDDEN; ++k) {
            float h = (float)((int)(signed char)ldsb[r * HROW + ((r & 7) << 4) + k]) * dq;
            sum = fmaf(h, Wo[c * HIDDEN + k], sum);
        }
        out[(b0 + r) * OUT_DIM + c] = sum;
    }
}

extern "C" void kernel_launch(void* const* d_in, const int* in_sizes, int n_in,
                              void* d_out, int out_size, void* d_ws, size_t ws_size,
                              hipStream_t stream) {
    const float* x  = (const float*)d_in[0];
    const float* h0 = (const float*)d_in[1];
    const float* Wi = (const float*)d_in[2];
    const float* Wh = (const float*)d_in[3];
    const float* Wo = (const float*)d_in[4];
    float* out = (float*)d_out;
    rnn_kernel<<<dim3(BATCH / MT), dim3(512), 0, stream>>>(x, h0, Wi, Wh, Wo, out);
}